// Round 1
// baseline (334.511 us; speedup 1.0000x reference)
//
#include <hip/hip_runtime.h>
#include <hip/hip_bf16.h>

typedef unsigned long long ull;

#define MGRID 48
#define CCH   256
#define NCELL 2304      // 48*48
#define NA    6912      // anchors
#define NW    108       // NA/64
#define NHID  1024
#define KFC   2304      // 9*256
#define RPOST 512
#define IMGF  1536.0f

__device__ inline ull shfl64(ull v, int lane){
  unsigned lo = (unsigned)__shfl((int)(unsigned)(v & 0xffffffffull), lane);
  unsigned hi = (unsigned)__shfl((int)(unsigned)(v >> 32), lane);
  return ((ull)hi << 32) | (ull)lo;
}

// ---------------- K1: RPN head: per (cell, o) dot product ----------------
__global__ __launch_bounds__(256) void rpn_head(const float* __restrict__ feat,
    const float* __restrict__ Wobj, const float* __restrict__ bobj,
    const float* __restrict__ Wreg, const float* __restrict__ breg,
    float* __restrict__ rpn){
  int g = blockIdx.x*256 + threadIdx.x;   // 2304*18 = 41472 threads
  int cell = g / 18, o = g % 18;
  const float* x = feat + cell*CCH;
  const float* W; int stride; float acc;
  if (o < 6){ W = Wobj + o; stride = 6;  acc = bobj[o];   }
  else      { W = Wreg + (o-6); stride = 12; acc = breg[o-6]; }
  #pragma unroll 8
  for (int c=0;c<CCH;++c) acc += x[c]*W[c*stride];
  rpn[cell*18 + o] = acc;
}

// ---------------- K2: per-anchor softmax, box decode, sort key ----------------
__global__ __launch_bounds__(256) void anchor_prep(const float* __restrict__ rpn,
    const float* __restrict__ anchors, float* __restrict__ probs,
    float* __restrict__ boxes, ull* __restrict__ keys){
  int a = blockIdx.x*256 + threadIdx.x;   // 6912
  int cell = a/3, k = a%3;
  const float* rc = rpn + cell*18;
  float l0 = rc[2*k], l1 = rc[2*k+1];
  float m  = fmaxf(l0,l1);
  float e0 = expf(l0-m), e1 = expf(l1-m);
  float s  = e0 + e1;
  float p0 = e0/s, p1 = e1/s;
  probs[a*2+0] = p0; probs[a*2+1] = p1;
  float4 an = ((const float4*)anchors)[a];
  float r0 = rc[6+4*k+0], r1 = rc[6+4*k+1], r2 = rc[6+4*k+2], r3 = rc[6+4*k+3];
  float cxa = an.x + an.z*0.5f, cya = an.y + an.w*0.5f;
  float cx = r0*an.z + cxa, cy = r1*an.w + cya;
  float w  = an.z*expf(r2),  hh = an.w*expf(r3);
  float bx = cx - w*0.5f, by = cy - hh*0.5f;
  float x1 = fminf(fmaxf(bx,      0.0f), IMGF);
  float y1 = fminf(fmaxf(by,      0.0f), IMGF);
  float x2 = fminf(fmaxf(bx + w,  0.0f), IMGF);
  float y2 = fminf(fmaxf(by + hh, 0.0f), IMGF);
  float4 bo; bo.x = x1; bo.y = y1; bo.z = x2 - x1; bo.w = y2 - y1;
  ((float4*)boxes)[a] = bo;
  // descending score, ties -> lower index first (stable argsort semantics)
  keys[a] = ((ull)__float_as_uint(p1) << 32) | (unsigned)(NA-1-a);
}

// ---------------- K3: O(n^2) rank sort (keys in LDS) ----------------
__global__ __launch_bounds__(256) void rank_sort(const ull* __restrict__ keys,
    const float* __restrict__ boxes, int* __restrict__ ord, float* __restrict__ sboxes){
  __shared__ ull lk[NA];
  int t = threadIdx.x;
  for (int idx=t; idx<NA; idx+=256) lk[idx] = keys[idx];
  __syncthreads();
  int i = blockIdx.x*256 + t;
  ull ki = lk[i];
  int rank = 0;
  #pragma unroll 8
  for (int j=0;j<NA;++j) rank += (lk[j] > ki) ? 1 : 0;
  ord[rank] = i;
  ((float4*)sboxes)[rank] = ((const float4*)boxes)[i];
}

// ---------------- K4: IoU suppression bitmask (transposed layout) ----------------
// maskT[w*NA + i] : bit jj set iff IoU(box_i, box_{w*64+jj}) > 0.3
__global__ __launch_bounds__(256) void iou_mask(const float* __restrict__ sboxes,
                                                ull* __restrict__ maskT){
  int gid = blockIdx.x*256 + threadIdx.x;  // 6912*108 threads
  int i = gid % NA;
  int w = gid / NA;
  float4 bi = ((const float4*)sboxes)[i];
  float x1i = bi.x, y1i = bi.y;
  float x2i = bi.x + bi.z, y2i = bi.y + bi.w;
  float ai  = (x2i - x1i) * (y2i - y1i);
  const float4* bj4 = (const float4*)sboxes + w*64;
  ull bits = 0;
  #pragma unroll 8
  for (int jj=0;jj<64;++jj){
    float4 bj = bj4[jj];                      // uniform across wave -> broadcast
    float x1j = bj.x, y1j = bj.y;
    float x2j = bj.x + bj.z, y2j = bj.y + bj.w;
    float aj  = (x2j - x1j) * (y2j - y1j);
    float iw = fmaxf(fminf(x2i,x2j) - fmaxf(x1i,x1j), 0.0f);
    float ih = fmaxf(fminf(y2i,y2j) - fmaxf(y1i,y1j), 0.0f);
    float inter = iw*ih;
    float den = ai + aj - inter + 1e-8f;
    if (inter > 0.3f*den) bits |= (1ull<<jj);
  }
  maskT[(size_t)w*NA + i] = bits;
}

// ---------------- K5: sequential greedy NMS scan + top-512 select ----------------
__global__ __launch_bounds__(256) void nms_scan(const ull* __restrict__ maskT,
    const int* __restrict__ ord, const float* __restrict__ sboxes,
    const float* __restrict__ probs, float* __restrict__ out, float* __restrict__ selb){
  __shared__ ull remv[NW];
  __shared__ ull keepw[NW];
  __shared__ ull kb_sh;
  __shared__ int selpos[RPOST];
  __shared__ int cnt_sh, done_sh;
  int t = threadIdx.x;
  if (t < NW){ remv[t] = 0ull; keepw[t] = 0ull; }
  if (t == 0){ cnt_sh = 0; done_sh = 0; }
  __syncthreads();

  for (int c=0; c<NW; ++c){
    // phase A: wave 0 serially resolves the 64-chunk
    if (t < 64){
      ull w = remv[c];
      ull diag = maskT[(size_t)c*NA + c*64 + t];
      ull kb = 0;
      for (int b=0;b<64;++b){
        ull rowb = shfl64(diag, b);
        ull nk = (~(w >> b)) & 1ull;        // 1 if kept
        kb |= nk << b;
        w  |= (0ull - nk) & rowb;
      }
      int cnt0 = cnt_sh;
      ull below = kb & ((t==0) ? 0ull : ((1ull << t) - 1ull));
      int myrank = cnt0 + __popcll(below);
      if (((kb >> t) & 1ull) && myrank < RPOST) selpos[myrank] = c*64 + t;
      if (t == 0){
        kb_sh = kb;
        keepw[c] = kb;
        int nc = cnt0 + __popcll(kb);
        if (nc >= RPOST){ nc = RPOST; done_sh = 1; }
        cnt_sh = nc;
      }
    }
    __syncthreads();
    if (done_sh) break;                      // top-512 complete: uniform exit
    // phase B: OR kept rows into future remv words (one word per thread)
    {
      ull kb = kb_sh;
      int wp = c + 1 + t;
      if (wp < NW && kb){
        ull acc = remv[wp];
        const ull* col = maskT + (size_t)wp*NA + c*64;   // 64 contiguous qwords
        #pragma unroll
        for (int b=0;b<64;++b)
          acc |= (0ull - ((kb >> b) & 1ull)) & col[b];
        remv[wp] = acc;
      }
    }
    __syncthreads();
  }
  __syncthreads();
  // fill path (only when full scan finished with <512 kept): suppressed, ascending
  if (t == 0 && cnt_sh < RPOST){
    int cnt = cnt_sh;
    for (int p=0; p<NA && cnt<RPOST; ++p)
      if (!((keepw[p>>6] >> (p&63)) & 1ull)) selpos[cnt++] = p;
    cnt_sh = cnt;
  }
  __syncthreads();
  for (int s=t; s<RPOST; s+=256){
    int pos = selpos[s];
    int orig = ord[pos];
    float4 b = ((const float4*)sboxes)[pos];
    out[s*10+0] = probs[orig*2+0];
    out[s*10+1] = probs[orig*2+1];
    out[s*10+2] = b.x; out[s*10+3] = b.y; out[s*10+4] = b.z; out[s*10+5] = b.w;
    ((float4*)selb)[s] = b;
  }
}

// ---------------- K6: ROIAlign (block = box, thread = channel) ----------------
__global__ __launch_bounds__(256) void roialign(const float* __restrict__ feat,
    const float* __restrict__ selb, float* __restrict__ pooled){
  int r = blockIdx.x, c = threadIdx.x;
  float4 b = ((const float4*)selb)[r];
  int x0[6], x1[6], y0[6], y1[6];
  float wx[6], wy[6];
  #pragma unroll
  for (int s=0;s<6;++s){
    float off = ((float)s + 0.5f) / 6.0f;
    float fx = (b.x + off*b.z) / 32.0f - 0.5f;
    fx = fminf(fmaxf(fx, 0.0f), 47.0f);
    int xx0 = (int)floorf(fx);
    x0[s] = xx0; x1[s] = min(xx0+1, 47); wx[s] = fx - (float)xx0;
    float fy = (b.y + off*b.w) / 32.0f - 0.5f;
    fy = fminf(fmaxf(fy, 0.0f), 47.0f);
    int yy0 = (int)floorf(fy);
    y0[s] = yy0; y1[s] = min(yy0+1, 47); wy[s] = fy - (float)yy0;
  }
  #pragma unroll
  for (int ty=0;ty<3;++ty){
    #pragma unroll
    for (int tx=0;tx<3;++tx){
      float sum = 0.0f;
      #pragma unroll
      for (int py=0;py<2;++py){
        #pragma unroll
        for (int px=0;px<2;++px){
          int sy = ty*2+py, sx = tx*2+px;
          float wxx = wx[sx], wyy = wy[sy];
          float v00 = feat[(y0[sy]*MGRID + x0[sx])*CCH + c];
          float v01 = feat[(y0[sy]*MGRID + x1[sx])*CCH + c];
          float v10 = feat[(y1[sy]*MGRID + x0[sx])*CCH + c];
          float v11 = feat[(y1[sy]*MGRID + x1[sx])*CCH + c];
          sum += v00*(1.0f-wyy)*(1.0f-wxx) + v01*(1.0f-wyy)*wxx
               + v10*wyy*(1.0f-wxx)        + v11*wyy*wxx;
        }
      }
      pooled[((r*9) + ty*3 + tx)*CCH + c] = sum * 0.25f;
    }
  }
}

// ---------------- K7: FC1 (512x2304 @ 2304x1024) + bias + ReLU ----------------
__global__ __launch_bounds__(256) void fc1(const float* __restrict__ A,
    const float* __restrict__ B, const float* __restrict__ bias, float* __restrict__ H){
  __shared__ float As[16][64];
  __shared__ float Bs[16][64];
  int t = threadIdx.x;
  int bn = blockIdx.x;   // 0..15 (N)
  int bm = blockIdx.y;   // 0..7  (M)
  int tx = t & 15, ty = t >> 4;
  int ar = t >> 2,  ak  = (t & 3) * 4;   // A loader: row, k-base
  int bkr = t >> 4, bc4 = (t & 15) * 4;  // B loader: k-row, col-base
  const float* Aptr = A + (size_t)(bm*64 + ar)*KFC + ak;
  const float* Bptr = B + (size_t)bkr*NHID + bn*64 + bc4;
  float c[4][4] = {};
  for (int kt=0; kt<KFC/16; ++kt){
    float4 a4 = *(const float4*)(Aptr + kt*16);
    float4 b4 = *(const float4*)(Bptr + (size_t)kt*16*NHID);
    As[ak+0][ar] = a4.x; As[ak+1][ar] = a4.y; As[ak+2][ar] = a4.z; As[ak+3][ar] = a4.w;
    *(float4*)&Bs[bkr][bc4] = b4;
    __syncthreads();
    #pragma unroll
    for (int k=0;k<16;++k){
      float4 av = *(const float4*)&As[k][ty*4];
      float4 bv = *(const float4*)&Bs[k][tx*4];
      c[0][0] += av.x*bv.x; c[0][1] += av.x*bv.y; c[0][2] += av.x*bv.z; c[0][3] += av.x*bv.w;
      c[1][0] += av.y*bv.x; c[1][1] += av.y*bv.y; c[1][2] += av.y*bv.z; c[1][3] += av.y*bv.w;
      c[2][0] += av.z*bv.x; c[2][1] += av.z*bv.y; c[2][2] += av.z*bv.z; c[2][3] += av.z*bv.w;
      c[3][0] += av.w*bv.x; c[3][1] += av.w*bv.y; c[3][2] += av.w*bv.z; c[3][3] += av.w*bv.w;
    }
    __syncthreads();
  }
  #pragma unroll
  for (int i=0;i<4;++i){
    int row = bm*64 + ty*4 + i;
    #pragma unroll
    for (int j=0;j<4;++j){
      int col = bn*64 + tx*4 + j;
      float v = c[i][j] + bias[col];
      H[(size_t)row*NHID + col] = fmaxf(v, 0.0f);
    }
  }
}

// ---------------- K8: FC2 + unparameterize (one wave per ROI) ----------------
__global__ __launch_bounds__(64) void fc2(const float* __restrict__ h,
    const float* __restrict__ W2, const float* __restrict__ b2,
    const float* __restrict__ selb, float* __restrict__ out){
  int r = blockIdx.x, lane = threadIdx.x;
  float a0=0,a1=0,a2=0,a3=0;
  #pragma unroll 4
  for (int it=0; it<16; ++it){
    int k = it*64 + lane;
    float hv = h[(size_t)r*NHID + k];
    float4 w = ((const float4*)W2)[k];
    a0 += hv*w.x; a1 += hv*w.y; a2 += hv*w.z; a3 += hv*w.w;
  }
  #pragma unroll
  for (int off=32; off>0; off>>=1){
    a0 += __shfl_down(a0, off);
    a1 += __shfl_down(a1, off);
    a2 += __shfl_down(a2, off);
    a3 += __shfl_down(a3, off);
  }
  if (lane == 0){
    float4 b = ((const float4*)selb)[r];
    float r0 = a0 + b2[0], r1 = a1 + b2[1], r2 = a2 + b2[2], r3 = a3 + b2[3];
    float cxa = b.x + b.z*0.5f, cya = b.y + b.w*0.5f;
    float cx = r0*b.z + cxa, cy = r1*b.w + cya;
    float w  = b.z*expf(r2),  hh = b.w*expf(r3);
    out[r*10+6] = cx - w*0.5f;
    out[r*10+7] = cy - hh*0.5f;
    out[r*10+8] = w;
    out[r*10+9] = hh;
  }
}

extern "C" void kernel_launch(void* const* d_in, const int* in_sizes, int n_in,
                              void* d_out, int out_size, void* d_ws, size_t ws_size,
                              hipStream_t stream) {
  const float* feat    = (const float*)d_in[0];
  const float* anchors = (const float*)d_in[1];
  const float* Wobj    = (const float*)d_in[2];
  const float* bobj    = (const float*)d_in[3];
  const float* Wreg    = (const float*)d_in[4];
  const float* breg    = (const float*)d_in[5];
  const float* Wfc1    = (const float*)d_in[6];
  const float* bfc1    = (const float*)d_in[7];
  const float* Wfc2    = (const float*)d_in[8];
  const float* bfc2    = (const float*)d_in[9];
  float* out = (float*)d_out;
  char* ws = (char*)d_ws;

  float* rpn    = (float*)(ws + 0);          // 2304*18*4      = 165888
  float* probs  = (float*)(ws + 165888);     // 6912*2*4       = 55296
  float* boxes  = (float*)(ws + 221184);     // 6912*4*4       = 110592
  ull*   keys   = (ull*)  (ws + 331776);     // 6912*8         = 55296
  int*   ord    = (int*)  (ws + 387072);     // 6912*4         = 27648
  float* sboxes = (float*)(ws + 414720);     // 6912*4*4       = 110592
  ull*   maskT  = (ull*)  (ws + 525312);     // 108*6912*8     = 5971968
  float* selb   = (float*)(ws + 6497280);    // 512*4*4        = 8192
  float* pooled = (float*)(ws + 6505472);    // 512*2304*4     = 4718592
  float* h      = (float*)(ws + 11224064);   // 512*1024*4     = 2097152  (end 13321216)

  hipLaunchKernelGGL(rpn_head,    dim3(162),   dim3(256), 0, stream, feat, Wobj, bobj, Wreg, breg, rpn);
  hipLaunchKernelGGL(anchor_prep, dim3(27),    dim3(256), 0, stream, rpn, anchors, probs, boxes, keys);
  hipLaunchKernelGGL(rank_sort,   dim3(27),    dim3(256), 0, stream, keys, boxes, ord, sboxes);
  hipLaunchKernelGGL(iou_mask,    dim3(2916),  dim3(256), 0, stream, sboxes, maskT);
  hipLaunchKernelGGL(nms_scan,    dim3(1),     dim3(256), 0, stream, maskT, ord, sboxes, probs, out, selb);
  hipLaunchKernelGGL(roialign,    dim3(512),   dim3(256), 0, stream, feat, selb, pooled);
  hipLaunchKernelGGL(fc1,         dim3(16,8),  dim3(256), 0, stream, pooled, Wfc1, bfc1, h);
  hipLaunchKernelGGL(fc2,         dim3(512),   dim3(64),  0, stream, h, Wfc2, bfc2, selb, out);
}

// Round 2
// 236.564 us; speedup vs baseline: 1.4140x; 1.4140x over previous
//
#include <hip/hip_runtime.h>
#include <hip/hip_bf16.h>

typedef unsigned long long ull;

#define MGRID 48
#define CCH   256
#define NCELL 2304      // 48*48
#define NA    6912      // anchors
#define NW    108       // NA/64
#define NHID  1024
#define KFC   2304      // 9*256
#define RPOST 512
#define IMGF  1536.0f

typedef __attribute__((ext_vector_type(8))) short short8v;  // 8 bf16
typedef __attribute__((ext_vector_type(4))) float f32x4;

// ---------------- K1: RPN head: per (cell, o) dot product ----------------
__global__ __launch_bounds__(256) void rpn_head(const float* __restrict__ feat,
    const float* __restrict__ Wobj, const float* __restrict__ bobj,
    const float* __restrict__ Wreg, const float* __restrict__ breg,
    float* __restrict__ rpn){
  int g = blockIdx.x*256 + threadIdx.x;   // 2304*18 = 41472 threads
  int cell = g / 18, o = g % 18;
  const float* x = feat + cell*CCH;
  const float* W; int stride; float acc;
  if (o < 6){ W = Wobj + o; stride = 6;  acc = bobj[o];   }
  else      { W = Wreg + (o-6); stride = 12; acc = breg[o-6]; }
  #pragma unroll 8
  for (int c=0;c<CCH;++c) acc += x[c]*W[c*stride];
  rpn[cell*18 + o] = acc;
}

// ---------------- K2: per-anchor softmax, box decode, sort key ----------------
__global__ __launch_bounds__(256) void anchor_prep(const float* __restrict__ rpn,
    const float* __restrict__ anchors, float* __restrict__ probs,
    float* __restrict__ boxes, ull* __restrict__ keys){
  int a = blockIdx.x*256 + threadIdx.x;   // 6912
  int cell = a/3, k = a%3;
  const float* rc = rpn + cell*18;
  float l0 = rc[2*k], l1 = rc[2*k+1];
  float m  = fmaxf(l0,l1);
  float e0 = expf(l0-m), e1 = expf(l1-m);
  float s  = e0 + e1;
  float p0 = e0/s, p1 = e1/s;
  probs[a*2+0] = p0; probs[a*2+1] = p1;
  float4 an = ((const float4*)anchors)[a];
  float r0 = rc[6+4*k+0], r1 = rc[6+4*k+1], r2 = rc[6+4*k+2], r3 = rc[6+4*k+3];
  float cxa = an.x + an.z*0.5f, cya = an.y + an.w*0.5f;
  float cx = r0*an.z + cxa, cy = r1*an.w + cya;
  float w  = an.z*expf(r2),  hh = an.w*expf(r3);
  float bx = cx - w*0.5f, by = cy - hh*0.5f;
  float x1 = fminf(fmaxf(bx,      0.0f), IMGF);
  float y1 = fminf(fmaxf(by,      0.0f), IMGF);
  float x2 = fminf(fmaxf(bx + w,  0.0f), IMGF);
  float y2 = fminf(fmaxf(by + hh, 0.0f), IMGF);
  float4 bo; bo.x = x1; bo.y = y1; bo.z = x2 - x1; bo.w = y2 - y1;
  ((float4*)boxes)[a] = bo;
  // descending score, ties -> lower index first (stable argsort semantics)
  keys[a] = ((ull)__float_as_uint(p1) << 32) | (unsigned)(NA-1-a);
}

// ---------------- K3: O(n^2) rank sort (keys in LDS) ----------------
__global__ __launch_bounds__(256) void rank_sort(const ull* __restrict__ keys,
    const float* __restrict__ boxes, int* __restrict__ ord, float* __restrict__ sboxes){
  __shared__ ull lk[NA];
  int t = threadIdx.x;
  for (int idx=t; idx<NA; idx+=256) lk[idx] = keys[idx];
  __syncthreads();
  int i = blockIdx.x*256 + t;
  ull ki = lk[i];
  int rank = 0;
  #pragma unroll 8
  for (int j=0;j<NA;++j) rank += (lk[j] > ki) ? 1 : 0;
  ord[rank] = i;
  ((float4*)sboxes)[rank] = ((const float4*)boxes)[i];
}

// ---------------- K4: IoU suppression bitmask (transposed layout) ----------------
// maskT[w*NA + i] : bit jj set iff IoU(box_i, box_{w*64+jj}) > 0.3
__global__ __launch_bounds__(256) void iou_mask(const float* __restrict__ sboxes,
                                                ull* __restrict__ maskT){
  int gid = blockIdx.x*256 + threadIdx.x;  // 6912*108 threads
  int i = gid % NA;
  int w = gid / NA;
  float4 bi = ((const float4*)sboxes)[i];
  float x1i = bi.x, y1i = bi.y;
  float x2i = bi.x + bi.z, y2i = bi.y + bi.w;
  float ai  = (x2i - x1i) * (y2i - y1i);
  const float4* bj4 = (const float4*)sboxes + w*64;
  ull bits = 0;
  #pragma unroll 8
  for (int jj=0;jj<64;++jj){
    float4 bj = bj4[jj];                      // uniform across wave -> broadcast
    float x1j = bj.x, y1j = bj.y;
    float x2j = bj.x + bj.z, y2j = bj.y + bj.w;
    float aj  = (x2j - x1j) * (y2j - y1j);
    float iw = fmaxf(fminf(x2i,x2j) - fmaxf(x1i,x1j), 0.0f);
    float ih = fmaxf(fminf(y2i,y2j) - fmaxf(y1i,y1j), 0.0f);
    float inter = iw*ih;
    float den = ai + aj - inter + 1e-8f;
    if (inter > 0.3f*den) bits |= (1ull<<jj);
  }
  maskT[(size_t)w*NA + i] = bits;
}

// ---------------- K5: sequential greedy NMS scan + top-512 select ----------------
__global__ __launch_bounds__(256) void nms_scan(const ull* __restrict__ maskT,
    const int* __restrict__ ord, const float* __restrict__ sboxes,
    const float* __restrict__ probs, float* __restrict__ out, float* __restrict__ selb){
  __shared__ ull remv[NW];
  __shared__ ull keepw[NW];
  __shared__ ull diag_sh[2][64];
  __shared__ int selpos[RPOST];
  __shared__ int cnt_sh, done_sh;
  int t = threadIdx.x;
  if (t < NW){ remv[t] = 0ull; keepw[t] = 0ull; }
  if (t == 0){ cnt_sh = 0; done_sh = 0; }
  if (t < 64) diag_sh[0][t] = maskT[t];      // diag rows of chunk 0
  __syncthreads();

  for (int c=0; c<NW; ++c){
    // prefetch next chunk's diagonal rows into registers (hidden under scan+phase B)
    ull dreg = 0;
    if (t < 64 && c+1 < NW) dreg = maskT[(size_t)(c+1)*NA + (c+1)*64 + t];

    // uniform greedy scan over kept bits only (all threads redundantly)
    const ull* dg = diag_sh[c & 1];
    ull w = remv[c];
    ull kb = 0;
    ull avail = ~w;
    while (avail){
      int b = __ffsll(avail) - 1;
      kb |= 1ull << b;
      w |= dg[b];
      avail &= ~w;
    }
    if (t < 64){
      int cnt0 = cnt_sh;
      ull below = kb & ((t==0) ? 0ull : ((1ull << t) - 1ull));
      int myrank = cnt0 + __popcll(below);
      if (((kb >> t) & 1ull) && myrank < RPOST) selpos[myrank] = c*64 + t;
      if (t == 0){
        keepw[c] = kb;
        int nc = cnt0 + __popcll(kb);
        if (nc >= RPOST){ nc = RPOST; done_sh = 1; }
        cnt_sh = nc;
      }
    }
    __syncthreads();
    if (done_sh) break;                      // top-512 complete: uniform exit
    // phase B: OR kept rows into future remv words (one word per thread)
    {
      int wp = c + 1 + t;
      if (wp < NW && kb){
        ull acc = remv[wp];
        const ull* col = maskT + (size_t)wp*NA + c*64;   // 64 contiguous qwords
        #pragma unroll
        for (int b=0;b<64;++b)
          acc |= (0ull - ((kb >> b) & 1ull)) & col[b];
        remv[wp] = acc;
      }
    }
    if (t < 64 && c+1 < NW) diag_sh[(c+1) & 1][t] = dreg;
    __syncthreads();
  }
  __syncthreads();
  // fill path (only when full scan finished with <512 kept): suppressed, ascending
  if (t == 0 && cnt_sh < RPOST){
    int cnt = cnt_sh;
    for (int p=0; p<NA && cnt<RPOST; ++p)
      if (!((keepw[p>>6] >> (p&63)) & 1ull)) selpos[cnt++] = p;
    cnt_sh = cnt;
  }
  __syncthreads();
  for (int s=t; s<RPOST; s+=256){
    int pos = selpos[s];
    int orig = ord[pos];
    float4 b = ((const float4*)sboxes)[pos];
    out[s*10+0] = probs[orig*2+0];
    out[s*10+1] = probs[orig*2+1];
    out[s*10+2] = b.x; out[s*10+3] = b.y; out[s*10+4] = b.z; out[s*10+5] = b.w;
    ((float4*)selb)[s] = b;
  }
}

// ---------------- K6: W_fc1 transpose + f32->bf16 convert: Wt[n][k] ----------------
__global__ __launch_bounds__(256) void wcvt(const float* __restrict__ W, ushort* __restrict__ Wt){
  __shared__ float tile[32][33];
  int bx = blockIdx.x;   // n-tile (32 cols), 32 blocks
  int by = blockIdx.y;   // k-tile (32 rows), 72 blocks
  int tx = threadIdx.x & 31, ty = threadIdx.x >> 5;
  #pragma unroll
  for (int it=0; it<4; ++it)
    tile[ty + 8*it][tx] = W[(size_t)(by*32 + ty + 8*it)*NHID + bx*32 + tx];
  __syncthreads();
  #pragma unroll
  for (int it=0; it<4; ++it){
    __hip_bfloat16 b = __float2bfloat16(tile[tx][ty + 8*it]);
    Wt[(size_t)(bx*32 + ty + 8*it)*KFC + by*32 + tx] = *(ushort*)&b;
  }
}

// ---------------- K7: ROIAlign (block = box, thread = channel) -> bf16 pooled ----------------
__global__ __launch_bounds__(256) void roialign(const float* __restrict__ feat,
    const float* __restrict__ selb, __hip_bfloat16* __restrict__ pooled){
  int r = blockIdx.x, c = threadIdx.x;
  float4 b = ((const float4*)selb)[r];
  int x0[6], x1[6], y0[6], y1[6];
  float wx[6], wy[6];
  #pragma unroll
  for (int s=0;s<6;++s){
    float off = ((float)s + 0.5f) / 6.0f;
    float fx = (b.x + off*b.z) / 32.0f - 0.5f;
    fx = fminf(fmaxf(fx, 0.0f), 47.0f);
    int xx0 = (int)floorf(fx);
    x0[s] = xx0; x1[s] = min(xx0+1, 47); wx[s] = fx - (float)xx0;
    float fy = (b.y + off*b.w) / 32.0f - 0.5f;
    fy = fminf(fmaxf(fy, 0.0f), 47.0f);
    int yy0 = (int)floorf(fy);
    y0[s] = yy0; y1[s] = min(yy0+1, 47); wy[s] = fy - (float)yy0;
  }
  #pragma unroll
  for (int ty=0;ty<3;++ty){
    #pragma unroll
    for (int tx=0;tx<3;++tx){
      float sum = 0.0f;
      #pragma unroll
      for (int py=0;py<2;++py){
        #pragma unroll
        for (int px=0;px<2;++px){
          int sy = ty*2+py, sx = tx*2+px;
          float wxx = wx[sx], wyy = wy[sy];
          float v00 = feat[(y0[sy]*MGRID + x0[sx])*CCH + c];
          float v01 = feat[(y0[sy]*MGRID + x1[sx])*CCH + c];
          float v10 = feat[(y1[sy]*MGRID + x0[sx])*CCH + c];
          float v11 = feat[(y1[sy]*MGRID + x1[sx])*CCH + c];
          sum += v00*(1.0f-wyy)*(1.0f-wxx) + v01*(1.0f-wyy)*wxx
               + v10*wyy*(1.0f-wxx)        + v11*wyy*wxx;
        }
      }
      pooled[((r*9) + ty*3 + tx)*CCH + c] = __float2bfloat16(sum * 0.25f);
    }
  }
}

// ---------------- K8: FC1 bf16 MFMA: (512x2304) @ (2304x1024) + bias + ReLU ----------------
// A = pooled bf16 [512][2304]; Bt = Wt bf16 [1024][2304] (transposed); H f32 [512][1024]
__global__ __launch_bounds__(256) void fc1_mfma(const ushort* __restrict__ A,
    const ushort* __restrict__ Bt, const float* __restrict__ bias,
    float* __restrict__ H){
  __shared__ ushort As[4096];   // 64 rows x 64 k bf16, XOR-swizzled 16B chunks
  __shared__ ushort Bs[4096];
  const int t = threadIdx.x;
  const int bn = blockIdx.x, bm = blockIdx.y;
  const int wv = t >> 6, lane = t & 63;
  const int wm = (wv >> 1) * 32, wn = (wv & 1) * 32;

  // staging: 16B chunk s in {t, t+256}; row = s>>3, kchunk = s&7
  const int r0 = t >> 3, kc = t & 7;
  const int r1 = r0 + 32;
  const float4* gA0 = (const float4*)A  + (size_t)(bm*64 + r0)*288 + kc;  // 288 = 2304*2B/16B
  const float4* gA1 = (const float4*)A  + (size_t)(bm*64 + r1)*288 + kc;
  const float4* gB0 = (const float4*)Bt + (size_t)(bn*64 + r0)*288 + kc;
  const float4* gB1 = (const float4*)Bt + (size_t)(bn*64 + r1)*288 + kc;
  float4* sA0 = (float4*)As + ((r0<<3) | (kc ^ (r0&7)));
  float4* sA1 = (float4*)As + ((r1<<3) | (kc ^ (r1&7)));
  float4* sB0 = (float4*)Bs + ((r0<<3) | (kc ^ (r0&7)));
  float4* sB1 = (float4*)Bs + ((r1<<3) | (kc ^ (r1&7)));

  const int fr = lane & 15, fkg = lane >> 4;
  const int arow0 = wm + fr,      arow1 = wm + 16 + fr;
  const int brow0 = wn + fr,      brow1 = wn + 16 + fr;

  f32x4 acc00{}, acc01{}, acc10{}, acc11{};

  float4 pa0 = gA0[0], pa1 = gA1[0], pb0 = gB0[0], pb1 = gB1[0];
  for (int kt = 0; kt < KFC/64; ++kt){
    __syncthreads();                          // previous compute done; LDS writable
    *sA0 = pa0; *sA1 = pa1; *sB0 = pb0; *sB1 = pb1;
    if (kt + 1 < KFC/64){                     // T14: issue next tile's loads early
      pa0 = gA0[(kt+1)*8]; pa1 = gA1[(kt+1)*8];
      pb0 = gB0[(kt+1)*8]; pb1 = gB1[(kt+1)*8];
    }
    __syncthreads();                          // LDS tile ready
    #pragma unroll
    for (int kk2 = 0; kk2 < 2; ++kk2){
      int kidx = fkg + kk2*4;
      short8v a0 = *(const short8v*)(As + ((((arow0<<3) | (kidx ^ (arow0&7)))) << 3));
      short8v a1 = *(const short8v*)(As + ((((arow1<<3) | (kidx ^ (arow1&7)))) << 3));
      short8v b0 = *(const short8v*)(Bs + ((((brow0<<3) | (kidx ^ (brow0&7)))) << 3));
      short8v b1 = *(const short8v*)(Bs + ((((brow1<<3) | (kidx ^ (brow1&7)))) << 3));
      acc00 = __builtin_amdgcn_mfma_f32_16x16x32_bf16(a0, b0, acc00, 0, 0, 0);
      acc01 = __builtin_amdgcn_mfma_f32_16x16x32_bf16(a0, b1, acc01, 0, 0, 0);
      acc10 = __builtin_amdgcn_mfma_f32_16x16x32_bf16(a1, b0, acc10, 0, 0, 0);
      acc11 = __builtin_amdgcn_mfma_f32_16x16x32_bf16(a1, b1, acc11, 0, 0, 0);
    }
  }
  // epilogue: C/D layout col=lane&15, row=(lane>>4)*4+reg  [m89/m91 verified]
  const int orow = bm*64 + wm + (lane>>4)*4;
  const int ocol = bn*64 + wn + (lane&15);
  #pragma unroll
  for (int i=0;i<2;++i){
    #pragma unroll
    for (int j=0;j<2;++j){
      f32x4 a = (i==0) ? ((j==0)?acc00:acc01) : ((j==0)?acc10:acc11);
      #pragma unroll
      for (int reg=0;reg<4;++reg){
        int row = orow + i*16 + reg;
        int col = ocol + j*16;
        float v = a[reg] + bias[col];
        H[(size_t)row*NHID + col] = fmaxf(v, 0.0f);
      }
    }
  }
}

// ---------------- K9: FC2 + unparameterize (one wave per ROI) ----------------
__global__ __launch_bounds__(64) void fc2(const float* __restrict__ h,
    const float* __restrict__ W2, const float* __restrict__ b2,
    const float* __restrict__ selb, float* __restrict__ out){
  int r = blockIdx.x, lane = threadIdx.x;
  float a0=0,a1=0,a2=0,a3=0;
  #pragma unroll 4
  for (int it=0; it<16; ++it){
    int k = it*64 + lane;
    float hv = h[(size_t)r*NHID + k];
    float4 w = ((const float4*)W2)[k];
    a0 += hv*w.x; a1 += hv*w.y; a2 += hv*w.z; a3 += hv*w.w;
  }
  #pragma unroll
  for (int off=32; off>0; off>>=1){
    a0 += __shfl_down(a0, off);
    a1 += __shfl_down(a1, off);
    a2 += __shfl_down(a2, off);
    a3 += __shfl_down(a3, off);
  }
  if (lane == 0){
    float4 b = ((const float4*)selb)[r];
    float r0 = a0 + b2[0], r1 = a1 + b2[1], r2 = a2 + b2[2], r3 = a3 + b2[3];
    float cxa = b.x + b.z*0.5f, cya = b.y + b.w*0.5f;
    float cx = r0*b.z + cxa, cy = r1*b.w + cya;
    float w  = b.z*expf(r2),  hh = b.w*expf(r3);
    out[r*10+6] = cx - w*0.5f;
    out[r*10+7] = cy - hh*0.5f;
    out[r*10+8] = w;
    out[r*10+9] = hh;
  }
}

extern "C" void kernel_launch(void* const* d_in, const int* in_sizes, int n_in,
                              void* d_out, int out_size, void* d_ws, size_t ws_size,
                              hipStream_t stream) {
  const float* feat    = (const float*)d_in[0];
  const float* anchors = (const float*)d_in[1];
  const float* Wobj    = (const float*)d_in[2];
  const float* bobj    = (const float*)d_in[3];
  const float* Wreg    = (const float*)d_in[4];
  const float* breg    = (const float*)d_in[5];
  const float* Wfc1    = (const float*)d_in[6];
  const float* bfc1    = (const float*)d_in[7];
  const float* Wfc2    = (const float*)d_in[8];
  const float* bfc2    = (const float*)d_in[9];
  float* out = (float*)d_out;
  char* ws = (char*)d_ws;

  float* rpn    = (float*)(ws + 0);          // 165888
  float* probs  = (float*)(ws + 165888);     // 55296
  float* boxes  = (float*)(ws + 221184);     // 110592
  ull*   keys   = (ull*)  (ws + 331776);     // 55296
  int*   ord    = (int*)  (ws + 387072);     // 27648
  float* sboxes = (float*)(ws + 414720);     // 110592
  ull*   maskT  = (ull*)  (ws + 525312);     // 5971968 (dead after nms_scan)
  ushort* Wt    = (ushort*)(ws + 525312);    // 4718592 (ALIASES maskT; wcvt runs after nms_scan)
  float* selb   = (float*)(ws + 6497280);    // 8192
  __hip_bfloat16* pooled = (__hip_bfloat16*)(ws + 6505472); // 512*2304*2 = 2359296
  float* h      = (float*)(ws + 8864768);    // 512*1024*4 = 2097152 (end 10961920)

  hipLaunchKernelGGL(rpn_head,    dim3(162),     dim3(256), 0, stream, feat, Wobj, bobj, Wreg, breg, rpn);
  hipLaunchKernelGGL(anchor_prep, dim3(27),      dim3(256), 0, stream, rpn, anchors, probs, boxes, keys);
  hipLaunchKernelGGL(rank_sort,   dim3(27),      dim3(256), 0, stream, keys, boxes, ord, sboxes);
  hipLaunchKernelGGL(iou_mask,    dim3(2916),    dim3(256), 0, stream, sboxes, maskT);
  hipLaunchKernelGGL(nms_scan,    dim3(1),       dim3(256), 0, stream, maskT, ord, sboxes, probs, out, selb);
  hipLaunchKernelGGL(wcvt,        dim3(32,72),   dim3(256), 0, stream, Wfc1, Wt);
  hipLaunchKernelGGL(roialign,    dim3(512),     dim3(256), 0, stream, feat, selb, pooled);
  hipLaunchKernelGGL(fc1_mfma,    dim3(16,8),    dim3(256), 0, stream, (const ushort*)pooled, Wt, bfc1, h);
  hipLaunchKernelGGL(fc2,         dim3(512),     dim3(64),  0, stream, h, Wfc2, bfc2, selb, out);
}

// Round 3
// 143.835 us; speedup vs baseline: 2.3257x; 1.6447x over previous
//
#include <hip/hip_runtime.h>
#include <hip/hip_bf16.h>

typedef unsigned long long ull;

#define MGRID 48
#define CCH   256
#define NCELL 2304      // 48*48
#define NA    6912      // anchors
#define NW    108       // NA/64
#define NHID  1024
#define KFC   2304      // 9*256
#define RPOST 512
#define IMGF  1536.0f

typedef __attribute__((ext_vector_type(8))) short short8v;  // 8 bf16
typedef __attribute__((ext_vector_type(4))) float f32x4;

// ---------------- K1: RPN head: per (cell, o) dot product ----------------
__global__ __launch_bounds__(256) void rpn_head(const float* __restrict__ feat,
    const float* __restrict__ Wobj, const float* __restrict__ bobj,
    const float* __restrict__ Wreg, const float* __restrict__ breg,
    float* __restrict__ rpn){
  int g = blockIdx.x*256 + threadIdx.x;   // 2304*18 = 41472 threads
  int cell = g / 18, o = g % 18;
  const float* x = feat + cell*CCH;
  const float* W; int stride; float acc;
  if (o < 6){ W = Wobj + o; stride = 6;  acc = bobj[o];   }
  else      { W = Wreg + (o-6); stride = 12; acc = breg[o-6]; }
  #pragma unroll 8
  for (int c=0;c<CCH;++c) acc += x[c]*W[c*stride];
  rpn[cell*18 + o] = acc;
}

// ---------------- K2: per-anchor softmax, box decode, sort key ----------------
__global__ __launch_bounds__(256) void anchor_prep(const float* __restrict__ rpn,
    const float* __restrict__ anchors, float* __restrict__ probs,
    float* __restrict__ boxes, ull* __restrict__ keys){
  int a = blockIdx.x*256 + threadIdx.x;   // 6912
  int cell = a/3, k = a%3;
  const float* rc = rpn + cell*18;
  float l0 = rc[2*k], l1 = rc[2*k+1];
  float m  = fmaxf(l0,l1);
  float e0 = expf(l0-m), e1 = expf(l1-m);
  float s  = e0 + e1;
  float p0 = e0/s, p1 = e1/s;
  probs[a*2+0] = p0; probs[a*2+1] = p1;
  float4 an = ((const float4*)anchors)[a];
  float r0 = rc[6+4*k+0], r1 = rc[6+4*k+1], r2 = rc[6+4*k+2], r3 = rc[6+4*k+3];
  float cxa = an.x + an.z*0.5f, cya = an.y + an.w*0.5f;
  float cx = r0*an.z + cxa, cy = r1*an.w + cya;
  float w  = an.z*expf(r2),  hh = an.w*expf(r3);
  float bx = cx - w*0.5f, by = cy - hh*0.5f;
  float x1 = fminf(fmaxf(bx,      0.0f), IMGF);
  float y1 = fminf(fmaxf(by,      0.0f), IMGF);
  float x2 = fminf(fmaxf(bx + w,  0.0f), IMGF);
  float y2 = fminf(fmaxf(by + hh, 0.0f), IMGF);
  float4 bo; bo.x = x1; bo.y = y1; bo.z = x2 - x1; bo.w = y2 - y1;
  ((float4*)boxes)[a] = bo;
  // descending score, ties -> lower index first (stable argsort semantics)
  keys[a] = ((ull)__float_as_uint(p1) << 32) | (unsigned)(NA-1-a);
}

// ---------------- K3a: partial ranks: part[jb][i] = #{j in tile jb : key[j] > key[i]} ----------------
__global__ __launch_bounds__(256) void rank_part(const ull* __restrict__ keys,
                                                 int* __restrict__ part){
  __shared__ ull lk[256];
  int t = threadIdx.x;
  int ib = blockIdx.x, jb = blockIdx.y;
  lk[t] = keys[jb*256 + t];
  int i = ib*256 + t;
  ull ki = keys[i];
  __syncthreads();
  int cnt = 0;
  #pragma unroll 16
  for (int j=0;j<256;++j) cnt += (lk[j] > ki) ? 1 : 0;
  part[jb*NA + i] = cnt;
}

// ---------------- K3b: sum partials -> rank, scatter ord + sorted boxes ----------------
__global__ __launch_bounds__(256) void rank_scatter(const int* __restrict__ part,
    const float* __restrict__ boxes, int* __restrict__ ord, float* __restrict__ sboxes){
  int i = blockIdx.x*256 + threadIdx.x;
  int r = 0;
  #pragma unroll
  for (int jb=0;jb<27;++jb) r += part[jb*NA + i];
  ord[r] = i;
  ((float4*)sboxes)[r] = ((const float4*)boxes)[i];
}

// ---------------- K4: IoU suppression bitmask (transposed layout) ----------------
// maskT[w*NA + i] : bit jj set iff IoU(box_i, box_{w*64+jj}) > 0.3
__global__ __launch_bounds__(256) void iou_mask(const float* __restrict__ sboxes,
                                                ull* __restrict__ maskT){
  int gid = blockIdx.x*256 + threadIdx.x;  // 6912*108 threads
  int i = gid % NA;
  int w = gid / NA;
  float4 bi = ((const float4*)sboxes)[i];
  float x1i = bi.x, y1i = bi.y;
  float x2i = bi.x + bi.z, y2i = bi.y + bi.w;
  float ai  = (x2i - x1i) * (y2i - y1i);
  const float4* bj4 = (const float4*)sboxes + w*64;
  ull bits = 0;
  #pragma unroll 8
  for (int jj=0;jj<64;++jj){
    float4 bj = bj4[jj];                      // uniform across wave -> broadcast
    float x1j = bj.x, y1j = bj.y;
    float x2j = bj.x + bj.z, y2j = bj.y + bj.w;
    float aj  = (x2j - x1j) * (y2j - y1j);
    float iw = fmaxf(fminf(x2i,x2j) - fmaxf(x1i,x1j), 0.0f);
    float ih = fmaxf(fminf(y2i,y2j) - fmaxf(y1i,y1j), 0.0f);
    float inter = iw*ih;
    float den = ai + aj - inter + 1e-8f;
    if (inter > 0.3f*den) bits |= (1ull<<jj);
  }
  maskT[(size_t)w*NA + i] = bits;
}

// ---------------- K5: sequential greedy NMS scan + top-512 select ----------------
__global__ __launch_bounds__(256) void nms_scan(const ull* __restrict__ maskT,
    const int* __restrict__ ord, const float* __restrict__ sboxes,
    const float* __restrict__ probs, float* __restrict__ out, float* __restrict__ selb){
  __shared__ ull remv[NW];
  __shared__ ull keepw[NW];
  __shared__ ull diag_sh[2][64];
  __shared__ int selpos[RPOST];
  __shared__ int cnt_sh, done_sh;
  int t = threadIdx.x;
  if (t < NW){ remv[t] = 0ull; keepw[t] = 0ull; }
  if (t == 0){ cnt_sh = 0; done_sh = 0; }
  if (t < 64) diag_sh[0][t] = maskT[t];      // diag rows of chunk 0
  __syncthreads();

  for (int c=0; c<NW; ++c){
    // prefetch next chunk's diagonal rows into registers (hidden under scan+phase B)
    ull dreg = 0;
    if (t < 64 && c+1 < NW) dreg = maskT[(size_t)(c+1)*NA + (c+1)*64 + t];

    // uniform greedy scan over kept bits only (all threads redundantly)
    const ull* dg = diag_sh[c & 1];
    ull w = remv[c];
    ull kb = 0;
    ull avail = ~w;
    while (avail){
      int b = __ffsll(avail) - 1;
      kb |= 1ull << b;
      w |= dg[b];
      avail &= ~w;
    }
    if (t < 64){
      int cnt0 = cnt_sh;
      ull below = kb & ((t==0) ? 0ull : ((1ull << t) - 1ull));
      int myrank = cnt0 + __popcll(below);
      if (((kb >> t) & 1ull) && myrank < RPOST) selpos[myrank] = c*64 + t;
      if (t == 0){
        keepw[c] = kb;
        int nc = cnt0 + __popcll(kb);
        if (nc >= RPOST){ nc = RPOST; done_sh = 1; }
        cnt_sh = nc;
      }
    }
    __syncthreads();
    if (done_sh) break;                      // top-512 complete: uniform exit
    // phase B: OR kept rows into future remv words (one word per thread)
    {
      int wp = c + 1 + t;
      if (wp < NW && kb){
        ull acc = remv[wp];
        const ull* col = maskT + (size_t)wp*NA + c*64;   // 64 contiguous qwords
        #pragma unroll
        for (int b=0;b<64;++b)
          acc |= (0ull - ((kb >> b) & 1ull)) & col[b];
        remv[wp] = acc;
      }
    }
    if (t < 64 && c+1 < NW) diag_sh[(c+1) & 1][t] = dreg;
    __syncthreads();
  }
  __syncthreads();
  // fill path (only when full scan finished with <512 kept): suppressed, ascending
  if (t == 0 && cnt_sh < RPOST){
    int cnt = cnt_sh;
    for (int p=0; p<NA && cnt<RPOST; ++p)
      if (!((keepw[p>>6] >> (p&63)) & 1ull)) selpos[cnt++] = p;
    cnt_sh = cnt;
  }
  __syncthreads();
  for (int s=t; s<RPOST; s+=256){
    int pos = selpos[s];
    int orig = ord[pos];
    float4 b = ((const float4*)sboxes)[pos];
    out[s*10+0] = probs[orig*2+0];
    out[s*10+1] = probs[orig*2+1];
    out[s*10+2] = b.x; out[s*10+3] = b.y; out[s*10+4] = b.z; out[s*10+5] = b.w;
    ((float4*)selb)[s] = b;
  }
}

// ---------------- K6: W_fc1 transpose + f32->bf16 convert: Wt[n][k] ----------------
__global__ __launch_bounds__(256) void wcvt(const float* __restrict__ W, ushort* __restrict__ Wt){
  __shared__ float tile[32][33];
  int bx = blockIdx.x;   // n-tile (32 cols), 32 blocks
  int by = blockIdx.y;   // k-tile (32 rows), 72 blocks
  int tx = threadIdx.x & 31, ty = threadIdx.x >> 5;
  #pragma unroll
  for (int it=0; it<4; ++it)
    tile[ty + 8*it][tx] = W[(size_t)(by*32 + ty + 8*it)*NHID + bx*32 + tx];
  __syncthreads();
  #pragma unroll
  for (int it=0; it<4; ++it){
    __hip_bfloat16 b = __float2bfloat16(tile[tx][ty + 8*it]);
    Wt[(size_t)(bx*32 + ty + 8*it)*KFC + by*32 + tx] = *(ushort*)&b;
  }
}

// ---------------- K7: ROIAlign (block = box, thread = channel) -> bf16 pooled ----------------
__global__ __launch_bounds__(256) void roialign(const float* __restrict__ feat,
    const float* __restrict__ selb, __hip_bfloat16* __restrict__ pooled){
  int r = blockIdx.x, c = threadIdx.x;
  float4 b = ((const float4*)selb)[r];
  int x0[6], x1[6], y0[6], y1[6];
  float wx[6], wy[6];
  #pragma unroll
  for (int s=0;s<6;++s){
    float off = ((float)s + 0.5f) / 6.0f;
    float fx = (b.x + off*b.z) / 32.0f - 0.5f;
    fx = fminf(fmaxf(fx, 0.0f), 47.0f);
    int xx0 = (int)floorf(fx);
    x0[s] = xx0; x1[s] = min(xx0+1, 47); wx[s] = fx - (float)xx0;
    float fy = (b.y + off*b.w) / 32.0f - 0.5f;
    fy = fminf(fmaxf(fy, 0.0f), 47.0f);
    int yy0 = (int)floorf(fy);
    y0[s] = yy0; y1[s] = min(yy0+1, 47); wy[s] = fy - (float)yy0;
  }
  #pragma unroll
  for (int ty=0;ty<3;++ty){
    #pragma unroll
    for (int tx=0;tx<3;++tx){
      float sum = 0.0f;
      #pragma unroll
      for (int py=0;py<2;++py){
        #pragma unroll
        for (int px=0;px<2;++px){
          int sy = ty*2+py, sx = tx*2+px;
          float wxx = wx[sx], wyy = wy[sy];
          float v00 = feat[(y0[sy]*MGRID + x0[sx])*CCH + c];
          float v01 = feat[(y0[sy]*MGRID + x1[sx])*CCH + c];
          float v10 = feat[(y1[sy]*MGRID + x0[sx])*CCH + c];
          float v11 = feat[(y1[sy]*MGRID + x1[sx])*CCH + c];
          sum += v00*(1.0f-wyy)*(1.0f-wxx) + v01*(1.0f-wyy)*wxx
               + v10*wyy*(1.0f-wxx)        + v11*wyy*wxx;
        }
      }
      pooled[((r*9) + ty*3 + tx)*CCH + c] = __float2bfloat16(sum * 0.25f);
    }
  }
}

// ---------------- K8: FC1 bf16 MFMA: (512x2304) @ (2304x1024) + bias + ReLU ----------------
// A = pooled bf16 [512][2304]; Bt = Wt bf16 [1024][2304] (transposed); H f32 [512][1024]
__global__ __launch_bounds__(256) void fc1_mfma(const ushort* __restrict__ A,
    const ushort* __restrict__ Bt, const float* __restrict__ bias,
    float* __restrict__ H){
  __shared__ ushort As[4096];   // 64 rows x 64 k bf16, XOR-swizzled 16B chunks
  __shared__ ushort Bs[4096];
  const int t = threadIdx.x;
  const int bn = blockIdx.x, bm = blockIdx.y;
  const int wv = t >> 6, lane = t & 63;
  const int wm = (wv >> 1) * 32, wn = (wv & 1) * 32;

  // staging: 16B chunk s in {t, t+256}; row = s>>3, kchunk = s&7
  const int r0 = t >> 3, kc = t & 7;
  const int r1 = r0 + 32;
  const float4* gA0 = (const float4*)A  + (size_t)(bm*64 + r0)*288 + kc;  // 288 = 2304*2B/16B
  const float4* gA1 = (const float4*)A  + (size_t)(bm*64 + r1)*288 + kc;
  const float4* gB0 = (const float4*)Bt + (size_t)(bn*64 + r0)*288 + kc;
  const float4* gB1 = (const float4*)Bt + (size_t)(bn*64 + r1)*288 + kc;
  float4* sA0 = (float4*)As + ((r0<<3) | (kc ^ (r0&7)));
  float4* sA1 = (float4*)As + ((r1<<3) | (kc ^ (r1&7)));
  float4* sB0 = (float4*)Bs + ((r0<<3) | (kc ^ (r0&7)));
  float4* sB1 = (float4*)Bs + ((r1<<3) | (kc ^ (r1&7)));

  const int fr = lane & 15, fkg = lane >> 4;
  const int arow0 = wm + fr,      arow1 = wm + 16 + fr;
  const int brow0 = wn + fr,      brow1 = wn + 16 + fr;

  f32x4 acc00{}, acc01{}, acc10{}, acc11{};

  float4 pa0 = gA0[0], pa1 = gA1[0], pb0 = gB0[0], pb1 = gB1[0];
  for (int kt = 0; kt < KFC/64; ++kt){
    __syncthreads();                          // previous compute done; LDS writable
    *sA0 = pa0; *sA1 = pa1; *sB0 = pb0; *sB1 = pb1;
    if (kt + 1 < KFC/64){                     // T14: issue next tile's loads early
      pa0 = gA0[(kt+1)*8]; pa1 = gA1[(kt+1)*8];
      pb0 = gB0[(kt+1)*8]; pb1 = gB1[(kt+1)*8];
    }
    __syncthreads();                          // LDS tile ready
    #pragma unroll
    for (int kk2 = 0; kk2 < 2; ++kk2){
      int kidx = fkg + kk2*4;
      short8v a0 = *(const short8v*)(As + ((((arow0<<3) | (kidx ^ (arow0&7)))) << 3));
      short8v a1 = *(const short8v*)(As + ((((arow1<<3) | (kidx ^ (arow1&7)))) << 3));
      short8v b0 = *(const short8v*)(Bs + ((((brow0<<3) | (kidx ^ (brow0&7)))) << 3));
      short8v b1 = *(const short8v*)(Bs + ((((brow1<<3) | (kidx ^ (brow1&7)))) << 3));
      acc00 = __builtin_amdgcn_mfma_f32_16x16x32_bf16(a0, b0, acc00, 0, 0, 0);
      acc01 = __builtin_amdgcn_mfma_f32_16x16x32_bf16(a0, b1, acc01, 0, 0, 0);
      acc10 = __builtin_amdgcn_mfma_f32_16x16x32_bf16(a1, b0, acc10, 0, 0, 0);
      acc11 = __builtin_amdgcn_mfma_f32_16x16x32_bf16(a1, b1, acc11, 0, 0, 0);
    }
  }
  // epilogue: C/D layout col=lane&15, row=(lane>>4)*4+reg  [m89/m91 verified]
  const int orow = bm*64 + wm + (lane>>4)*4;
  const int ocol = bn*64 + wn + (lane&15);
  #pragma unroll
  for (int i=0;i<2;++i){
    #pragma unroll
    for (int j=0;j<2;++j){
      f32x4 a = (i==0) ? ((j==0)?acc00:acc01) : ((j==0)?acc10:acc11);
      #pragma unroll
      for (int reg=0;reg<4;++reg){
        int row = orow + i*16 + reg;
        int col = ocol + j*16;
        float v = a[reg] + bias[col];
        H[(size_t)row*NHID + col] = fmaxf(v, 0.0f);
      }
    }
  }
}

// ---------------- K9: FC2 + unparameterize (one wave per ROI) ----------------
__global__ __launch_bounds__(64) void fc2(const float* __restrict__ h,
    const float* __restrict__ W2, const float* __restrict__ b2,
    const float* __restrict__ selb, float* __restrict__ out){
  int r = blockIdx.x, lane = threadIdx.x;
  float a0=0,a1=0,a2=0,a3=0;
  #pragma unroll 4
  for (int it=0; it<16; ++it){
    int k = it*64 + lane;
    float hv = h[(size_t)r*NHID + k];
    float4 w = ((const float4*)W2)[k];
    a0 += hv*w.x; a1 += hv*w.y; a2 += hv*w.z; a3 += hv*w.w;
  }
  #pragma unroll
  for (int off=32; off>0; off>>=1){
    a0 += __shfl_down(a0, off);
    a1 += __shfl_down(a1, off);
    a2 += __shfl_down(a2, off);
    a3 += __shfl_down(a3, off);
  }
  if (lane == 0){
    float4 b = ((const float4*)selb)[r];
    float r0 = a0 + b2[0], r1 = a1 + b2[1], r2 = a2 + b2[2], r3 = a3 + b2[3];
    float cxa = b.x + b.z*0.5f, cya = b.y + b.w*0.5f;
    float cx = r0*b.z + cxa, cy = r1*b.w + cya;
    float w  = b.z*expf(r2),  hh = b.w*expf(r3);
    out[r*10+6] = cx - w*0.5f;
    out[r*10+7] = cy - hh*0.5f;
    out[r*10+8] = w;
    out[r*10+9] = hh;
  }
}

extern "C" void kernel_launch(void* const* d_in, const int* in_sizes, int n_in,
                              void* d_out, int out_size, void* d_ws, size_t ws_size,
                              hipStream_t stream) {
  const float* feat    = (const float*)d_in[0];
  const float* anchors = (const float*)d_in[1];
  const float* Wobj    = (const float*)d_in[2];
  const float* bobj    = (const float*)d_in[3];
  const float* Wreg    = (const float*)d_in[4];
  const float* breg    = (const float*)d_in[5];
  const float* Wfc1    = (const float*)d_in[6];
  const float* bfc1    = (const float*)d_in[7];
  const float* Wfc2    = (const float*)d_in[8];
  const float* bfc2    = (const float*)d_in[9];
  float* out = (float*)d_out;
  char* ws = (char*)d_ws;

  float* rpn    = (float*)(ws + 0);          // 165888
  float* probs  = (float*)(ws + 165888);     // 55296
  float* boxes  = (float*)(ws + 221184);     // 110592
  ull*   keys   = (ull*)  (ws + 331776);     // 55296
  int*   ord    = (int*)  (ws + 387072);     // 27648
  float* sboxes = (float*)(ws + 414720);     // 110592
  int*   part   = (int*)  (ws + 525312);     // 27*6912*4 = 746496 (dead after rank_scatter)
  ull*   maskT  = (ull*)  (ws + 1271808);    // 5971968 (dead after nms_scan)
  ushort* Wt    = (ushort*)(ws + 1271808);   // 4718592 (ALIASES maskT; wcvt runs after nms_scan)
  float* selb   = (float*)(ws + 7243776);    // 8192
  __hip_bfloat16* pooled = (__hip_bfloat16*)(ws + 7251968); // 512*2304*2 = 2359296
  float* h      = (float*)(ws + 9611264);    // 512*1024*4 = 2097152 (end 11708416)

  hipLaunchKernelGGL(rpn_head,     dim3(162),     dim3(256), 0, stream, feat, Wobj, bobj, Wreg, breg, rpn);
  hipLaunchKernelGGL(anchor_prep,  dim3(27),      dim3(256), 0, stream, rpn, anchors, probs, boxes, keys);
  hipLaunchKernelGGL(rank_part,    dim3(27,27),   dim3(256), 0, stream, keys, part);
  hipLaunchKernelGGL(rank_scatter, dim3(27),      dim3(256), 0, stream, part, boxes, ord, sboxes);
  hipLaunchKernelGGL(iou_mask,     dim3(2916),    dim3(256), 0, stream, sboxes, maskT);
  hipLaunchKernelGGL(nms_scan,     dim3(1),       dim3(256), 0, stream, maskT, ord, sboxes, probs, out, selb);
  hipLaunchKernelGGL(wcvt,         dim3(32,72),   dim3(256), 0, stream, Wfc1, Wt);
  hipLaunchKernelGGL(roialign,     dim3(512),     dim3(256), 0, stream, feat, selb, pooled);
  hipLaunchKernelGGL(fc1_mfma,     dim3(16,8),    dim3(256), 0, stream, (const ushort*)pooled, Wt, bfc1, h);
  hipLaunchKernelGGL(fc2,          dim3(512),     dim3(64),  0, stream, h, Wfc2, bfc2, selb, out);
}